// Round 12
// baseline (255.953 us; speedup 1.0000x reference)
//
#include <hip/hip_runtime.h>

typedef int v4i __attribute__((ext_vector_type(4)));

#define KDIM 2048
#define NDIM 2048

#define GLOAD16(g, l) __builtin_amdgcn_global_load_lds(                      \
    (const __attribute__((address_space(1))) void*)(g),                      \
    (__attribute__((address_space(3))) void*)(l), 16, 0, 0)

// ---------------- quant kernels ----------------

__device__ __forceinline__ int pack4q(float4 v, float s) {
  int a = __float2int_rn(v.x * s);
  int b = __float2int_rn(v.y * s);
  int c = __float2int_rn(v.z * s);
  int d = __float2int_rn(v.w * s);
  a = max(-128, min(127, a)); b = max(-128, min(127, b));
  c = max(-128, min(127, c)); d = max(-128, min(127, d));
  return (a & 0xff) | ((b & 0xff) << 8) | ((c & 0xff) << 16) | ((d & 0xff) << 24);
}

__global__ __launch_bounds__(256) void quant_rows(const float* __restrict__ x,
                                                  signed char* __restrict__ q,
                                                  float* __restrict__ rscale) {
  const int row = blockIdx.x;
  const float4* xr = (const float4*)(x + (size_t)row * KDIM);
  float4 v0 = xr[threadIdx.x];
  float4 v1 = xr[256 + threadIdx.x];
  float m = fmaxf(fmaxf(fabsf(v0.x), fabsf(v0.y)), fmaxf(fabsf(v0.z), fabsf(v0.w)));
  m = fmaxf(m, fmaxf(fmaxf(fabsf(v1.x), fabsf(v1.y)), fmaxf(fabsf(v1.z), fabsf(v1.w))));
  #pragma unroll
  for (int off = 32; off > 0; off >>= 1) m = fmaxf(m, __shfl_xor(m, off));
  __shared__ float red[4];
  if ((threadIdx.x & 63) == 0) red[threadIdx.x >> 6] = m;
  __syncthreads();
  float xmax = fmaxf(fmaxf(red[0], red[1]), fmaxf(red[2], red[3]));
  xmax = fmaxf(xmax, 1e-5f);
  const float scale = 127.0f / xmax;
  int* qr = (int*)(q + (size_t)row * KDIM);
  qr[threadIdx.x] = pack4q(v0, scale);
  qr[256 + threadIdx.x] = pack4q(v1, scale);
  if (threadIdx.x == 0) rscale[row] = xmax * (1.0f / 127.0f);
}

__global__ __launch_bounds__(256) void quant_w(const float* __restrict__ W,
                                               signed char* __restrict__ Wq) {
  const int i = blockIdx.x * 256 + threadIdx.x;
  float4 v = ((const float4*)W)[i];
  int a = (int)v.x, b = (int)v.y, c = (int)v.z, d = (int)v.w;
  ((int*)Wq)[i] = (a & 0xff) | ((b << 8) & 0xff00) | ((c << 16) & 0xff0000) | (d << 24);
}

// ---- 256x256 8-wave i8 GEMM, ring-4, counted vmcnt, FUSED ROUNDS (round-12) ----
// Round-12: only change vs R10 = 16 barrier-rounds x 2 K-tiles (was 32 x 1).
// Tests the per-round-overhead hypothesis (all 7 prior variants had 32 rounds and
// identical ~3260 cyc/tile; MFMA needs only 1306). Per round:
//   [24 ds_read_b128 (tiles T,T+1)] -> barrier + lgkmcnt(0)   (reads complete)
//   [stage tiles T+4,T+5 into the just-freed slots: 8 gloads]
//   [64 MFMA] -> vmcnt(8) (waits pair T+2,T+3; leaves T+4,T+5 in flight) -> barrier
// Sync per tile: 1 barrier / 0.5 lgkm0 / 0.5 vmcnt  (was 4 / 2 / 1).
// MFMA shape 16x16x64 and the R4-verified 0-conflict swizzle (phys 16B slot =
// logical ^ ((row>>1)&3), both on global source and ds_read) are unchanged.

#define VM8 asm volatile("s_waitcnt vmcnt(8)" ::: "memory")
#define VM0 asm volatile("s_waitcnt vmcnt(0)" ::: "memory")
#define VMNONE

#define STAGE_A(U, T)                                                        \
  GLOAD16(sa + (T) * 64, lds + (U) * 32768 + dstw);                          \
  GLOAD16(sa + (T) * 64 + 128 * KDIM, lds + (U) * 32768 + 8192 + dstw);
#define STAGE_B(U, T)                                                        \
  GLOAD16(sb + (T) * 64, lds + (U) * 32768 + 16384 + dstw);                  \
  GLOAD16(sb + (T) * 64 + 128 * KDIM, lds + (U) * 32768 + 24576 + dstw);

#define READS(U, P)                                                          \
  v4i P##a0 = *(const v4i*)(lds + (U) * 32768 + aRd);                        \
  v4i P##a1 = *(const v4i*)(lds + (U) * 32768 + aRd + 1024);                 \
  v4i P##a2 = *(const v4i*)(lds + (U) * 32768 + aRd + 2048);                 \
  v4i P##a3 = *(const v4i*)(lds + (U) * 32768 + aRd + 3072);                 \
  v4i P##a4 = *(const v4i*)(lds + (U) * 32768 + aRd + 4096);                 \
  v4i P##a5 = *(const v4i*)(lds + (U) * 32768 + aRd + 5120);                 \
  v4i P##a6 = *(const v4i*)(lds + (U) * 32768 + aRd + 6144);                 \
  v4i P##a7 = *(const v4i*)(lds + (U) * 32768 + aRd + 7168);                 \
  v4i P##b0 = *(const v4i*)(lds + (U) * 32768 + bRd);                        \
  v4i P##b1 = *(const v4i*)(lds + (U) * 32768 + bRd + 1024);                 \
  v4i P##b2 = *(const v4i*)(lds + (U) * 32768 + bRd + 2048);                 \
  v4i P##b3 = *(const v4i*)(lds + (U) * 32768 + bRd + 3072);

#define MF1(m, n, A, B) acc[m][n] = __builtin_amdgcn_mfma_i32_16x16x64_i8((A), (B), acc[m][n], 0, 0, 0);
#define MFROW(m, P) MF1(m, 0, P##a##m, P##b0) MF1(m, 1, P##a##m, P##b1)      \
                    MF1(m, 2, P##a##m, P##b2) MF1(m, 3, P##a##m, P##b3)
#define MFT(P) MFROW(0, P) MFROW(1, P) MFROW(2, P) MFROW(3, P)               \
               MFROW(4, P) MFROW(5, P) MFROW(6, P) MFROW(7, P)

// U in {0,2}: consume slots U,U+1 (tiles T,T+1); stage T+4,T+5 into same slots.
#define KPAIR(U, T, DOSTAGE, VMEND)                                          \
  {                                                                          \
    READS((U), fX)                                                           \
    READS((U) + 1, fY)                                                       \
    __builtin_amdgcn_sched_barrier(0);                                       \
    __builtin_amdgcn_s_barrier();                                            \
    asm volatile("s_waitcnt lgkmcnt(0)" ::: "memory");                       \
    __builtin_amdgcn_sched_barrier(0);                                       \
    if (DOSTAGE) {                                                           \
      STAGE_A((U), (T) + 4) STAGE_B((U), (T) + 4)                            \
      STAGE_A((U) + 1, (T) + 5) STAGE_B((U) + 1, (T) + 5)                    \
    }                                                                        \
    __builtin_amdgcn_sched_barrier(0);                                       \
    __builtin_amdgcn_s_setprio(1);                                           \
    MFT(fX)                                                                  \
    MFT(fY)                                                                  \
    __builtin_amdgcn_s_setprio(0);                                           \
    __builtin_amdgcn_sched_barrier(0);                                       \
    VMEND;                                                                   \
    __builtin_amdgcn_s_barrier();                                            \
  }

__global__ __launch_bounds__(512, 2) void gemm_i8(const signed char* __restrict__ A,
                                                  const signed char* __restrict__ B,
                                                  const float* __restrict__ rscale,
                                                  float* __restrict__ C) {
  __shared__ __align__(16) signed char lds[131072];
  const int bid = blockIdx.x;
  const int lid = (bid & 7) * 128 + (bid >> 3);  // bijective XCD swizzle (1024 % 8 == 0)
  const int bm = lid >> 3;                       // 128 row tiles
  const int bn = lid & 7;                        // 8 col tiles
  const int tid = threadIdx.x;
  const int wid = tid >> 6;
  const int lane = tid & 63;
  const int wr = wid >> 2, wc = wid & 3;

  // staging: thread covers row = wid*16 + (lane>>2) within each 128-row half,
  // dest slot = lane&3 (HW linear: base + lane*16).
  // source logical slot = (lane&3) ^ ((row>>1)&3) = (lane&3) ^ ((lane>>3)&3).  [R4-verified]
  const int srow = wid * 16 + (lane >> 2);
  const int scol = (((lane & 3) ^ ((lane >> 3) & 3)) << 4);
  const signed char* sa = A + (size_t)(bm * 256 + srow) * KDIM + scol;
  const signed char* sb = B + (size_t)(bn * 256 + srow) * KDIM + scol;
  const int dstw = wid << 10;  // wave-uniform LDS chunk; HW adds lane*16

  // ds_read: logical k-slot = lane>>4, row = ...+(lane&15) -> physical slot
  // = (lane>>4) ^ ((lane>>1)&3).  [R4-verified: SQ_LDS_BANK_CONFLICT = 0]
  const int rslot = (((lane >> 4) ^ ((lane >> 1) & 3)) << 4);
  const int aRd = (wr * 128 + (lane & 15)) * 64 + rslot;
  const int bRd = 16384 + (wc * 64 + (lane & 15)) * 64 + rslot;

  v4i acc[8][4] = {};

  // prologue: stage tiles 0-3 (fills ring); VM8 => tiles 0,1 complete, 2,3 in flight.
  STAGE_A(0, 0) STAGE_B(0, 0)
  STAGE_A(1, 1) STAGE_B(1, 1)
  STAGE_A(2, 2) STAGE_B(2, 2)
  STAGE_A(3, 3) STAGE_B(3, 3)
  VM8;
  __builtin_amdgcn_s_barrier();

  // 16 rounds x 2 tiles. Rounds 0..13 stage (tiles 4..31).
  for (int r2 = 0; r2 < 7; ++r2) {
    const int t = r2 * 4;
    KPAIR(0, t + 0, 1, VM8)
    KPAIR(2, t + 2, 1, VM8)
  }
  KPAIR(0, 28, 0, VM0)     // waits tiles 30,31 (last in flight)
  KPAIR(2, 30, 0, VMNONE)

  // epilogue: C/D layout col = lane&15, row = (lane>>4)*4 + reg
  const int col0 = bn * 256 + wc * 64 + (lane & 15);
  const int rbase = bm * 256 + wr * 128 + ((lane >> 4) << 2);
  #pragma unroll
  for (int m = 0; m < 8; ++m) {
    #pragma unroll
    for (int r = 0; r < 4; ++r) {
      const int row = rbase + m * 16 + r;
      const float s = rscale[row];
      float* crow = C + (size_t)row * NDIM + col0;
      #pragma unroll
      for (int n = 0; n < 4; ++n) crow[n * 16] = (float)acc[m][n][r] * s;
    }
  }
}

extern "C" void kernel_launch(void* const* d_in, const int* in_sizes, int n_in,
                              void* d_out, int out_size, void* d_ws, size_t ws_size,
                              hipStream_t stream) {
  const float* x = (const float*)d_in[0];
  const float* W = (const float*)d_in[1];
  float* out = (float*)d_out;
  const int M = in_sizes[0] / KDIM;  // 32768

  signed char* q = (signed char*)d_ws;                       // M*K   = 64 MB
  signed char* Wq = q + (size_t)M * KDIM;                    // N*K   =  4 MB
  float* rscale = (float*)(Wq + (size_t)NDIM * KDIM);        // M*4   = 128 KB

  quant_rows<<<M, 256, 0, stream>>>(x, q, rscale);
  quant_w<<<(NDIM * KDIM / 4) / 256, 256, 0, stream>>>(W, Wq);
  gemm_i8<<<(M / 256) * (NDIM / 256), 512, 0, stream>>>(q, Wq, rscale, out);
}